// Round 1
// baseline (13119.003 us; speedup 1.0000x reference)
//
#include <hip/hip_runtime.h>
#include <math.h>

// ---------------- problem constants (NT=1, REAL=512 fixed by harness inputs) --
#define BB    2
#define SS    1024
#define EE    768
#define NH    8
#define DHD   96
#define NL    8
#define FFD   2048
#define VD    32000
#define REALC 512
#define MTOK  (BB*SS)     // 2048 rows for layer ops
#define MACTN (BB*REALC)  // 1024 rows for head ops
#define QKVW  (3*EE)      // 2304

static __device__ __forceinline__ float gelu_exact(float x) {
    return 0.5f * x * (1.0f + erff(x * 0.7071067811865476f));
}

// ---------------- embed: h = x + pe(r) + tpe(p) --------------------------------
__global__ __launch_bounds__(256) void embed_kernel(const float* __restrict__ x,
                                                    const float* __restrict__ tpe,
                                                    float* __restrict__ h) {
    int idx = blockIdx.x * 256 + threadIdx.x;   // over MTOK*EE
    if (idx >= MTOK * EE) return;
    int e = idx % EE;
    int tok = idx / EE;          // b*SS + s
    int s = tok & (SS - 1);
    int r = s >> 1;              // s / bs
    int p = s & 1;               // s % bs
    int k2 = (e >> 1) * 2;       // even index used in arange(0,E,2)
    double div = exp((double)k2 * (-9.210340371976184 / (double)EE)); // ln(10000)
    double ang = (double)r * div;
    float pe = (e & 1) ? (float)cos(ang) : (float)sin(ang);
    h[idx] = x[idx] + pe + tpe[p * EE + e];
}

// ---------------- fp32 tiled GEMM: C[m,n] = sum_k A[m,k]*W[n,k] + bias[n] ------
// tiles 64x64, BK=16, 256 threads, 4x4 per thread. M%64==0, N%64==0, K%16==0.
template<bool GELU>
__global__ __launch_bounds__(256) void gemm_kernel(const float* __restrict__ A,
                                                   const float* __restrict__ W,
                                                   const float* __restrict__ bias,
                                                   float* __restrict__ C,
                                                   int M, int N, int K) {
    __shared__ float As[16][64];
    __shared__ float Ws[16][64];
    const int bm = blockIdx.y * 64;
    const int bn = blockIdx.x * 64;
    const int t  = threadIdx.x;
    const int lm  = t >> 2;          // 0..63 (tile row for loading)
    const int lk4 = (t & 3) << 2;    // 0,4,8,12
    const int tm  = (t >> 4) << 2;   // 0..60
    const int tn  = (t & 15) << 2;   // 0..60
    float acc[4][4] = {};
    const float* Arow = A + (size_t)(bm + lm) * K + lk4;
    const float* Wrow = W + (size_t)(bn + lm) * K + lk4;
    for (int k0 = 0; k0 < K; k0 += 16) {
        float4 av = *(const float4*)(Arow + k0);
        float4 wv = *(const float4*)(Wrow + k0);
        __syncthreads();
        As[lk4 + 0][lm] = av.x; As[lk4 + 1][lm] = av.y;
        As[lk4 + 2][lm] = av.z; As[lk4 + 3][lm] = av.w;
        Ws[lk4 + 0][lm] = wv.x; Ws[lk4 + 1][lm] = wv.y;
        Ws[lk4 + 2][lm] = wv.z; Ws[lk4 + 3][lm] = wv.w;
        __syncthreads();
#pragma unroll
        for (int kk = 0; kk < 16; ++kk) {
            float4 a = *(const float4*)&As[kk][tm];
            float4 w = *(const float4*)&Ws[kk][tn];
            float ar[4] = {a.x, a.y, a.z, a.w};
            float wr[4] = {w.x, w.y, w.z, w.w};
#pragma unroll
            for (int i = 0; i < 4; ++i)
#pragma unroll
                for (int j = 0; j < 4; ++j)
                    acc[i][j] = fmaf(ar[i], wr[j], acc[i][j]);
        }
    }
#pragma unroll
    for (int i = 0; i < 4; ++i) {
        const size_t row = (size_t)(bm + tm + i);
        float4 out;
        float* po = C + row * (size_t)N + bn + tn;
        float b0 = bias[bn + tn + 0], b1 = bias[bn + tn + 1];
        float b2 = bias[bn + tn + 2], b3 = bias[bn + tn + 3];
        out.x = acc[i][0] + b0; out.y = acc[i][1] + b1;
        out.z = acc[i][2] + b2; out.w = acc[i][3] + b3;
        if (GELU) {
            out.x = gelu_exact(out.x); out.y = gelu_exact(out.y);
            out.z = gelu_exact(out.z); out.w = gelu_exact(out.w);
        }
        *(float4*)po = out;
    }
}

// ---------------- attention: one block per (b, head, q) ------------------------
// qkv row layout per token: [q(768) | k(768) | v(768)], head hh at hh*96.
__global__ __launch_bounds__(128) void attn_kernel(const float* __restrict__ qkv,
                                                   float* __restrict__ o) {
    __shared__ float sc[SS];
    __shared__ float qv[DHD];
    __shared__ float red[128];
    const int bid = blockIdx.x;
    const int q  = bid & (SS - 1);
    const int hh = (bid >> 10) & (NH - 1);
    const int b  = bid >> 13;
    const int t  = threadIdx.x;
    const size_t stride = QKVW;
    const float* base = qkv + (size_t)b * SS * stride;
    const float scale = 0.10206207261596577f; // 1/sqrt(96)

    if (t < DHD) qv[t] = base[(size_t)q * stride + hh * DHD + t];
    __syncthreads();

    for (int k = t; k < SS; k += 128) {
        const float* krow = base + (size_t)k * stride + EE + hh * DHD;
        float acc = 0.f;
#pragma unroll 8
        for (int d = 0; d < DHD; ++d) acc = fmaf(qv[d], krow[d], acc);
        bool allowed = (((k >> 1) == (q >> 1)) && ((q & 1) >= (k & 1))) ||
                       (((k & 1) == 0) && (q > k));
        sc[k] = acc * scale + (allowed ? 0.f : 1.f);
    }
    __syncthreads();

    // block max
    float m = -1e30f;
    for (int k = t; k < SS; k += 128) m = fmaxf(m, sc[k]);
    red[t] = m; __syncthreads();
    for (int s2 = 64; s2 > 0; s2 >>= 1) {
        if (t < s2) red[t] = fmaxf(red[t], red[t + s2]);
        __syncthreads();
    }
    const float mx = red[0];
    __syncthreads();

    // exp + sum
    float sm = 0.f;
    for (int k = t; k < SS; k += 128) {
        float w = expf(sc[k] - mx);
        sc[k] = w;
        sm += w;
    }
    red[t] = sm; __syncthreads();
    for (int s2 = 64; s2 > 0; s2 >>= 1) {
        if (t < s2) red[t] += red[t + s2];
        __syncthreads();
    }
    const float inv = 1.0f / red[0];

    // o[d] = sum_k w[k] * V[k][d]
    if (t < DHD) {
        const float* vcol = base + 2 * EE + hh * DHD + t;
        float acc = 0.f;
        for (int k = 0; k < SS; ++k) acc = fmaf(sc[k], vcol[(size_t)k * stride], acc);
        o[(size_t)(b * SS + q) * EE + hh * DHD + t] = acc * inv;
    }
}

// ---------------- layernorm (+optional residual, +NaN->0), optional gather -----
template<bool GATHER>
__global__ __launch_bounds__(256) void ln_kernel(const float* __restrict__ a,
                                                 const float* __restrict__ res,
                                                 const float* __restrict__ g,
                                                 const float* __restrict__ beta,
                                                 float* __restrict__ out) {
    __shared__ float rs[256], rs2[256];
    const int row = blockIdx.x;
    const int t = threadIdx.x;
    int src = row;
    if (GATHER) src = (row >> 9) * SS + ((row & 511) << 1) + 1; // act_idx = 2r+1
    const float* pa = a + (size_t)src * EE;
    const float* pr = res ? res + (size_t)src * EE : nullptr;
    float x[3];
    float s = 0.f, s2 = 0.f;
#pragma unroll
    for (int i = 0; i < 3; ++i) {
        int e = t + i * 256;
        float v = pa[e] + (pr ? pr[e] : 0.f);
        x[i] = v; s += v; s2 += v * v;
    }
    rs[t] = s; rs2[t] = s2; __syncthreads();
    for (int k = 128; k > 0; k >>= 1) {
        if (t < k) { rs[t] += rs[t + k]; rs2[t] += rs2[t + k]; }
        __syncthreads();
    }
    const float mean = rs[0] * (1.0f / EE);
    const float var  = rs2[0] * (1.0f / EE) - mean * mean;
    const float rstd = 1.0f / sqrtf(var + 1e-5f);
#pragma unroll
    for (int i = 0; i < 3; ++i) {
        int e = t + i * 256;
        float v = (x[i] - mean) * rstd * g[e] + beta[e];
        if (isnan(v)) v = 0.f;  // nan_to_num
        out[(size_t)row * EE + e] = v;
    }
}

// ---------------- value head second GEMM (N=1) ---------------------------------
__global__ __launch_bounds__(256) void value2_kernel(const float* __restrict__ v1,
                                                     const float* __restrict__ Wv2,
                                                     const float* __restrict__ bv2,
                                                     float* __restrict__ out) {
    __shared__ float red[256];
    const int row = blockIdx.x;
    const int t = threadIdx.x;
    const float* pr = v1 + (size_t)row * FFD;
    float s = 0.f;
    for (int i = t; i < FFD; i += 256) s = fmaf(pr[i], Wv2[i], s);
    red[t] = s; __syncthreads();
    for (int k = 128; k > 0; k >>= 1) {
        if (t < k) red[t] += red[t + k];
        __syncthreads();
    }
    if (t == 0) out[row] = red[0] + bv2[0];
}

// ---------------- launch --------------------------------------------------------
extern "C" void kernel_launch(void* const* d_in, const int* in_sizes, int n_in,
                              void* d_out, int out_size, void* d_ws, size_t ws_size,
                              hipStream_t stream) {
    const float* x    = (const float*)d_in[0];
    const float* tpe  = (const float*)d_in[1];
    const float* Wqkv = (const float*)d_in[2];
    const float* bqkv = (const float*)d_in[3];
    const float* W1   = (const float*)d_in[4];
    const float* b1   = (const float*)d_in[5];
    const float* W2   = (const float*)d_in[6];
    const float* b2   = (const float*)d_in[7];
    const float* g1   = (const float*)d_in[8];
    const float* be1  = (const float*)d_in[9];
    const float* g2   = (const float*)d_in[10];
    const float* be2  = (const float*)d_in[11];
    const float* gf   = (const float*)d_in[12];
    const float* bf   = (const float*)d_in[13];
    const float* Wp1  = (const float*)d_in[14];
    const float* bp1  = (const float*)d_in[15];
    const float* Wp2  = (const float*)d_in[16];
    const float* bp2  = (const float*)d_in[17];
    const float* Wv1  = (const float*)d_in[18];
    const float* bv1  = (const float*)d_in[19];
    const float* Wv2  = (const float*)d_in[20];
    const float* bv2  = (const float*)d_in[21];

    // workspace layout (floats); aliasing: ff1/p1 reuse qkv region, act reuses o.
    float* ws  = (float*)d_ws;
    float* h   = ws;                      // 2048*768
    float* qkv = h   + (size_t)MTOK * EE; // 2048*2304 (also ff1, p1)
    float* o   = qkv + (size_t)MTOK * QKVW; // 2048*768 (also act)
    float* hc  = o   + (size_t)MTOK * EE; // 2048*768
    float* ff2 = hc  + (size_t)MTOK * EE; // 2048*768
    // total = 11,010,048 floats = 44 MB

    float* ff1 = qkv;
    float* act = o;
    float* p1  = qkv;
    float* pol = (float*)d_out;                       // 1024*32000
    float* val = (float*)d_out + (size_t)MACTN * VD;  // 1024

    embed_kernel<<<(MTOK * EE + 255) / 256, 256, 0, stream>>>(x, tpe, h);

    for (int l = 0; l < NL; ++l) {
        const float* Wq = Wqkv + (size_t)l * QKVW * EE;
        const float* bq = bqkv + (size_t)l * QKVW;
        gemm_kernel<false><<<dim3(QKVW / 64, MTOK / 64), 256, 0, stream>>>(
            h, Wq, bq, qkv, MTOK, QKVW, EE);
        attn_kernel<<<BB * NH * SS, 128, 0, stream>>>(qkv, o);
        ln_kernel<false><<<MTOK, 256, 0, stream>>>(h, o, g1 + l * EE, be1 + l * EE, hc);
        gemm_kernel<true><<<dim3(FFD / 64, MTOK / 64), 256, 0, stream>>>(
            hc, W1 + (size_t)l * FFD * EE, b1 + l * FFD, ff1, MTOK, FFD, EE);
        gemm_kernel<false><<<dim3(EE / 64, MTOK / 64), 256, 0, stream>>>(
            ff1, W2 + (size_t)l * EE * FFD, b2 + l * EE, ff2, MTOK, EE, FFD);
        ln_kernel<false><<<MTOK, 256, 0, stream>>>(hc, ff2, g2 + l * EE, be2 + l * EE, h);
    }

    // final LN on the 1024 action rows only (act_idx = 2r+1), gathered contiguous
    ln_kernel<true><<<MACTN, 256, 0, stream>>>(h, nullptr, gf, bf, act);

    // policy head
    gemm_kernel<true><<<dim3(FFD / 64, MACTN / 64), 256, 0, stream>>>(
        act, Wp1, bp1, p1, MACTN, FFD, EE);
    gemm_kernel<false><<<dim3(VD / 64, MACTN / 64), 256, 0, stream>>>(
        p1, Wp2, bp2, pol, MACTN, VD, FFD);

    // value head (reuse p1 after policy GEMM consumed it)
    gemm_kernel<true><<<dim3(FFD / 64, MACTN / 64), 256, 0, stream>>>(
        act, Wv1, bv1, p1, MACTN, FFD, EE);
    value2_kernel<<<MACTN, 256, 0, stream>>>(p1, Wv2, bv2, val);
}

// Round 2
// 9550.813 us; speedup vs baseline: 1.3736x; 1.3736x over previous
//
#include <hip/hip_runtime.h>
#include <math.h>

// ---------------- problem constants (NT=1, REAL=512 fixed by harness inputs) --
#define BB    2
#define SS    1024
#define EE    768
#define NH    8
#define DHD   96
#define NL    8
#define FFD   2048
#define VD    32000
#define REALC 512
#define MTOK  (BB*SS)     // 2048 rows for layer ops
#define MACTN (BB*REALC)  // 1024 rows for head ops
#define QKVW  (3*EE)      // 2304
#define WCHUNK 6400       // Wp2 N-chunk (32000 = 5*6400, 6400%128==0)

typedef __attribute__((ext_vector_type(8))) short bf16x8;
typedef __attribute__((ext_vector_type(4))) float f32x4;

static __device__ __forceinline__ float gelu_exact(float x) {
    return 0.5f * x * (1.0f + erff(x * 0.7071067811865476f));
}
static __device__ __forceinline__ unsigned short f2bf(float f) {
    unsigned int u = __builtin_bit_cast(unsigned int, f);
    unsigned int r = u + 0x7FFFu + ((u >> 16) & 1u);  // RNE (finite values only)
    return (unsigned short)(r >> 16);
}
static __device__ __forceinline__ float bf2f(unsigned short u) {
    union { unsigned int i; float f; } v; v.i = ((unsigned int)u) << 16; return v.f;
}

#define GLDS16(gp, lp) __builtin_amdgcn_global_load_lds( \
    (const __attribute__((address_space(1))) void*)(gp), \
    (__attribute__((address_space(3))) void*)(lp), 16, 0, 0)

// ---------------- fp32 -> bf16 convert (vectorized) -----------------------------
__global__ __launch_bounds__(256) void f2b_kernel(const float* __restrict__ src,
                                                  unsigned short* __restrict__ dst, int n4) {
    int i = blockIdx.x * 256 + threadIdx.x;
    if (i >= n4) return;
    float4 v = ((const float4*)src)[i];
    ushort4 o;
    o.x = f2bf(v.x); o.y = f2bf(v.y); o.z = f2bf(v.z); o.w = f2bf(v.w);
    ((ushort4*)dst)[i] = o;
}

// ---------------- embed: h = x + pe(r) + tpe(p), dual fp32+bf16 out -------------
__global__ __launch_bounds__(256) void embed_kernel(const float* __restrict__ x,
                                                    const float* __restrict__ tpe,
                                                    float* __restrict__ h,
                                                    unsigned short* __restrict__ hb) {
    int idx = blockIdx.x * 256 + threadIdx.x;   // over MTOK*EE
    if (idx >= MTOK * EE) return;
    int e = idx % EE;
    int tok = idx / EE;          // b*SS + s
    int s = tok & (SS - 1);
    int r = s >> 1;              // s / bs
    int p = s & 1;               // s % bs
    int k2 = (e >> 1) * 2;
    double div = exp((double)k2 * (-9.210340371976184 / (double)EE)); // ln(10000)
    double ang = (double)r * div;
    float pe = (e & 1) ? (float)cos(ang) : (float)sin(ang);
    float v = x[idx] + pe + tpe[p * EE + e];
    h[idx] = v;
    hb[idx] = f2bf(v);
}

// ---------------- bf16 MFMA GEMM: C[m,n] = A[m,:]·W[n,:] + bias[n] --------------
// m97 structure: 128x128 tile, BK=64, 4 waves (each 64x64 = 4x4 frags of 16x16),
// global_load_lds width-16 staging, linear LDS [128][64].
// MODE: 0 = fp32 out, 3 = bf16 out + GELU.  M%128==0, N%128==0, K%64==0.
template<int MODE>
__global__ __launch_bounds__(256) void gemm_bf16_kernel(
    const unsigned short* __restrict__ A, const unsigned short* __restrict__ W,
    const float* __restrict__ bias, float* __restrict__ Cf,
    unsigned short* __restrict__ Cb, int M, int N, int K, int ldc) {
    __shared__ unsigned short As[128 * 64];
    __shared__ unsigned short Ws[128 * 64];
    const int bm = blockIdx.y * 128;
    const int bn = blockIdx.x * 128;
    const int t = threadIdx.x;
    const int wave = t >> 6;
    const int lane = t & 63;
    const int wm = (wave >> 1) * 64;   // wave's output row offset in tile
    const int wn = (wave & 1) * 64;    // wave's output col offset in tile
    f32x4 acc[4][4] = {};

    // staging: wave w covers tile rows [w*32, w*32+32), 4 issues of 8 rows each;
    // lane l -> row +(l>>3), col elems (l&7)*8  (16B per lane, LDS linear match)
    const int srow = wave * 32 + (lane >> 3);
    const int scol = (lane & 7) * 8;
    const unsigned short* gA = A + (size_t)(bm + srow) * K + scol;
    const unsigned short* gW = W + (size_t)(bn + srow) * K + scol;

    for (int k0 = 0; k0 < K; k0 += 64) {
        __syncthreads();  // previous compute done before overwrite
#pragma unroll
        for (int i = 0; i < 4; ++i) {
            GLDS16(gA + (size_t)(i * 8) * K + k0, &As[(wave * 32 + i * 8) * 64]);
            GLDS16(gW + (size_t)(i * 8) * K + k0, &Ws[(wave * 32 + i * 8) * 64]);
        }
        __syncthreads();  // compiler drains vmcnt(0) before barrier
#pragma unroll
        for (int ks = 0; ks < 2; ++ks) {
            bf16x8 a[4], b[4];
#pragma unroll
            for (int mi = 0; mi < 4; ++mi)
                a[mi] = *(const bf16x8*)&As[(wm + mi * 16 + (lane & 15)) * 64 + ks * 32 + (lane >> 4) * 8];
#pragma unroll
            for (int ni = 0; ni < 4; ++ni)
                b[ni] = *(const bf16x8*)&Ws[(wn + ni * 16 + (lane & 15)) * 64 + ks * 32 + (lane >> 4) * 8];
#pragma unroll
            for (int mi = 0; mi < 4; ++mi)
#pragma unroll
                for (int ni = 0; ni < 4; ++ni)
                    acc[mi][ni] = __builtin_amdgcn_mfma_f32_16x16x32_bf16(
                        a[mi], b[ni], acc[mi][ni], 0, 0, 0);
        }
    }

    // epilogue: C/D layout col = lane&15, row = (lane>>4)*4 + r  [m89-verified]
#pragma unroll
    for (int mi = 0; mi < 4; ++mi) {
#pragma unroll
        for (int ni = 0; ni < 4; ++ni) {
            const int c = bn + wn + ni * 16 + (lane & 15);
            const float bv = bias[c];
#pragma unroll
            for (int r = 0; r < 4; ++r) {
                const int rw = bm + wm + mi * 16 + (lane >> 4) * 4 + r;
                float v = acc[mi][ni][r] + bv;
                if (MODE == 3) {
                    v = gelu_exact(v);
                    Cb[(size_t)rw * ldc + c] = f2bf(v);
                } else {
                    Cf[(size_t)rw * ldc + c] = v;
                }
            }
        }
    }
}

// ---------------- attention: one block per (b, head, q) ------------------------
__global__ __launch_bounds__(128) void attn_kernel(const float* __restrict__ qkv,
                                                   float* __restrict__ o) {
    __shared__ float sc[SS];
    __shared__ float qv[DHD];
    __shared__ float red[128];
    const int bid = blockIdx.x;
    const int q  = bid & (SS - 1);
    const int hh = (bid >> 10) & (NH - 1);
    const int b  = bid >> 13;
    const int t  = threadIdx.x;
    const size_t stride = QKVW;
    const float* base = qkv + (size_t)b * SS * stride;
    const float scale = 0.10206207261596577f; // 1/sqrt(96)

    if (t < DHD) qv[t] = base[(size_t)q * stride + hh * DHD + t];
    __syncthreads();

    for (int k = t; k < SS; k += 128) {
        const float* krow = base + (size_t)k * stride + EE + hh * DHD;
        float acc = 0.f;
#pragma unroll 8
        for (int d = 0; d < DHD; ++d) acc = fmaf(qv[d], krow[d], acc);
        bool allowed = (((k >> 1) == (q >> 1)) && ((q & 1) >= (k & 1))) ||
                       (((k & 1) == 0) && (q > k));
        sc[k] = acc * scale + (allowed ? 0.f : 1.f);
    }
    __syncthreads();

    float m = -1e30f;
    for (int k = t; k < SS; k += 128) m = fmaxf(m, sc[k]);
    red[t] = m; __syncthreads();
    for (int s2 = 64; s2 > 0; s2 >>= 1) {
        if (t < s2) red[t] = fmaxf(red[t], red[t + s2]);
        __syncthreads();
    }
    const float mx = red[0];
    __syncthreads();

    float sm = 0.f;
    for (int k = t; k < SS; k += 128) {
        float w = expf(sc[k] - mx);
        sc[k] = w;
        sm += w;
    }
    red[t] = sm; __syncthreads();
    for (int s2 = 64; s2 > 0; s2 >>= 1) {
        if (t < s2) red[t] += red[t + s2];
        __syncthreads();
    }
    const float inv = 1.0f / red[0];

    if (t < DHD) {
        const float* vcol = base + 2 * EE + hh * DHD + t;
        float acc = 0.f;
        for (int k = 0; k < SS; ++k) acc = fmaf(sc[k], vcol[(size_t)k * stride], acc);
        o[(size_t)(b * SS + q) * EE + hh * DHD + t] = acc * inv;
    }
}

// ---------------- layernorm (+residual, +NaN->0), dual out, optional gather ----
template<bool GATHER>
__global__ __launch_bounds__(256) void ln_kernel(const float* __restrict__ a,
                                                 const float* __restrict__ res,
                                                 const float* __restrict__ g,
                                                 const float* __restrict__ beta,
                                                 float* __restrict__ outf,
                                                 unsigned short* __restrict__ outb) {
    __shared__ float rs[256], rs2[256];
    const int row = blockIdx.x;
    const int t = threadIdx.x;
    int src = row;
    if (GATHER) src = (row >> 9) * SS + ((row & 511) << 1) + 1; // act_idx = 2r+1
    const float* pa = a + (size_t)src * EE;
    const float* pr = res ? res + (size_t)src * EE : nullptr;
    float x[3];
    float s = 0.f, s2 = 0.f;
#pragma unroll
    for (int i = 0; i < 3; ++i) {
        int e = t + i * 256;
        float v = pa[e] + (pr ? pr[e] : 0.f);
        x[i] = v; s += v; s2 += v * v;
    }
    rs[t] = s; rs2[t] = s2; __syncthreads();
    for (int k = 128; k > 0; k >>= 1) {
        if (t < k) { rs[t] += rs[t + k]; rs2[t] += rs2[t + k]; }
        __syncthreads();
    }
    const float mean = rs[0] * (1.0f / EE);
    const float var  = rs2[0] * (1.0f / EE) - mean * mean;
    const float rstd = 1.0f / sqrtf(var + 1e-5f);
#pragma unroll
    for (int i = 0; i < 3; ++i) {
        int e = t + i * 256;
        float v = (x[i] - mean) * rstd * g[e] + beta[e];
        if (isnan(v)) v = 0.f;  // nan_to_num
        if (outf) outf[(size_t)row * EE + e] = v;
        if (outb) outb[(size_t)row * EE + e] = f2bf(v);
    }
}

// ---------------- value head second GEMM (N=1), bf16 input ---------------------
__global__ __launch_bounds__(256) void value2_kernel(const unsigned short* __restrict__ v1,
                                                     const float* __restrict__ Wv2,
                                                     const float* __restrict__ bv2,
                                                     float* __restrict__ out) {
    __shared__ float red[256];
    const int row = blockIdx.x;
    const int t = threadIdx.x;
    const unsigned short* pr = v1 + (size_t)row * FFD;
    float s = 0.f;
    for (int i = t; i < FFD; i += 256) s = fmaf(bf2f(pr[i]), Wv2[i], s);
    red[t] = s; __syncthreads();
    for (int k = 128; k > 0; k >>= 1) {
        if (t < k) red[t] += red[t + k];
        __syncthreads();
    }
    if (t == 0) out[row] = red[0] + bv2[0];
}

// ---------------- launch --------------------------------------------------------
extern "C" void kernel_launch(void* const* d_in, const int* in_sizes, int n_in,
                              void* d_out, int out_size, void* d_ws, size_t ws_size,
                              hipStream_t stream) {
    const float* x    = (const float*)d_in[0];
    const float* tpe  = (const float*)d_in[1];
    const float* Wqkv = (const float*)d_in[2];
    const float* bqkv = (const float*)d_in[3];
    const float* W1   = (const float*)d_in[4];
    const float* b1   = (const float*)d_in[5];
    const float* W2   = (const float*)d_in[6];
    const float* b2   = (const float*)d_in[7];
    const float* g1   = (const float*)d_in[8];
    const float* be1  = (const float*)d_in[9];
    const float* g2   = (const float*)d_in[10];
    const float* be2  = (const float*)d_in[11];
    const float* gf   = (const float*)d_in[12];
    const float* bf   = (const float*)d_in[13];
    const float* Wp1  = (const float*)d_in[14];
    const float* bp1  = (const float*)d_in[15];
    const float* Wp2  = (const float*)d_in[16];
    const float* bp2  = (const float*)d_in[17];
    const float* Wv1  = (const float*)d_in[18];
    const float* bv1  = (const float*)d_in[19];
    const float* Wv2  = (const float*)d_in[20];
    const float* bv2  = (const float*)d_in[21];

    // ---- workspace layout ----
    float* ws  = (float*)d_ws;
    float* h   = ws;                         // 2048*768
    float* qkv = h   + (size_t)MTOK * EE;    // 2048*2304
    float* o   = qkv + (size_t)MTOK * QKVW;  // 2048*768
    float* hc  = o   + (size_t)MTOK * EE;    // 2048*768
    float* ff2 = hc  + (size_t)MTOK * EE;    // 2048*768
    unsigned short* bws = (unsigned short*)(ff2 + (size_t)MTOK * EE);
    unsigned short* h_bf   = bws;                                   // 2048*768
    unsigned short* hc_bf  = h_bf  + (size_t)MTOK * EE;             // 2048*768
    unsigned short* ff1_bf = hc_bf + (size_t)MTOK * EE;             // 2048*2048
    unsigned short* act_bf = ff1_bf + (size_t)MTOK * FFD;           // 1024*768
    unsigned short* p1_bf  = act_bf + (size_t)MACTN * EE;           // 1024*2048 (also v1)
    unsigned short* wb     = p1_bf  + (size_t)MACTN * FFD;          // layer weights: 4,915,200
    unsigned short* wq_bf  = wb;                                    // 2304*768
    unsigned short* w1_bf  = wq_bf + (size_t)QKVW * EE;             // 2048*768
    unsigned short* w2_bf  = w1_bf + (size_t)FFD * EE;              // 768*2048
    unsigned short* wp1_bf = wb;                                    // 2048*768 (reuse)
    unsigned short* wv1_bf = wb + (size_t)FFD * EE;                 // 2048*768
    unsigned short* wp2c   = wb + (size_t)QKVW * EE + 2 * (size_t)FFD * EE; // 6400*2048
    // total ws ~= 100.5 MB

    float* pol = (float*)d_out;                       // 1024*32000
    float* val = (float*)d_out + (size_t)MACTN * VD;  // 1024

    const int C256 = 256;
#define NBLK(n) (((n) + 255) / 256)
#define CONV(src, dst, n) f2b_kernel<<<NBLK((n) / 4), C256, 0, stream>>>(src, dst, (n) / 4)

    embed_kernel<<<NBLK(MTOK * EE), C256, 0, stream>>>(x, tpe, h, h_bf);

    for (int l = 0; l < NL; ++l) {
        CONV(Wqkv + (size_t)l * QKVW * EE, wq_bf, QKVW * EE);
        CONV(W1   + (size_t)l * FFD * EE,  w1_bf, FFD * EE);
        CONV(W2   + (size_t)l * EE * FFD,  w2_bf, EE * FFD);

        gemm_bf16_kernel<0><<<dim3(QKVW / 128, MTOK / 128), C256, 0, stream>>>(
            h_bf, wq_bf, bqkv + (size_t)l * QKVW, qkv, nullptr, MTOK, QKVW, EE, QKVW);
        attn_kernel<<<BB * NH * SS, 128, 0, stream>>>(qkv, o);
        ln_kernel<false><<<MTOK, C256, 0, stream>>>(h, o, g1 + l * EE, be1 + l * EE, hc, hc_bf);
        gemm_bf16_kernel<3><<<dim3(FFD / 128, MTOK / 128), C256, 0, stream>>>(
            hc_bf, w1_bf, b1 + (size_t)l * FFD, nullptr, ff1_bf, MTOK, FFD, EE, FFD);
        gemm_bf16_kernel<0><<<dim3(EE / 128, MTOK / 128), C256, 0, stream>>>(
            ff1_bf, w2_bf, b2 + (size_t)l * EE, ff2, nullptr, MTOK, EE, FFD, EE);
        ln_kernel<false><<<MTOK, C256, 0, stream>>>(hc, ff2, g2 + l * EE, be2 + l * EE, h, h_bf);
    }

    // final LN on the 1024 action rows (act_idx = 2r+1), bf16 out only
    ln_kernel<true><<<MACTN, C256, 0, stream>>>(h, nullptr, gf, bf, nullptr, act_bf);

    // policy head: p1 = gelu(act @ Wp1^T + bp1) in bf16; pol = p1 @ Wp2^T + bp2 (chunked)
    CONV(Wp1, wp1_bf, FFD * EE);
    gemm_bf16_kernel<3><<<dim3(FFD / 128, MACTN / 128), C256, 0, stream>>>(
        act_bf, wp1_bf, bp1, nullptr, p1_bf, MACTN, FFD, EE, FFD);
    for (int c = 0; c < VD / WCHUNK; ++c) {
        CONV(Wp2 + (size_t)c * WCHUNK * FFD, wp2c, WCHUNK * FFD);
        gemm_bf16_kernel<0><<<dim3(WCHUNK / 128, MACTN / 128), C256, 0, stream>>>(
            p1_bf, wp2c, bp2 + (size_t)c * WCHUNK, pol + (size_t)c * WCHUNK, nullptr,
            MACTN, WCHUNK, FFD, VD);
    }

    // value head (reuse p1_bf after policy GEMM consumed it)
    CONV(Wv1, wv1_bf, FFD * EE);
    gemm_bf16_kernel<3><<<dim3(FFD / 128, MACTN / 128), C256, 0, stream>>>(
        act_bf, wv1_bf, bv1, nullptr, p1_bf, MACTN, FFD, EE, FFD);
    value2_kernel<<<MACTN, C256, 0, stream>>>(p1_bf, Wv2, bv2, val);
#undef CONV
#undef NBLK
}

// Round 3
// 1614.963 us; speedup vs baseline: 8.1234x; 5.9140x over previous
//
#include <hip/hip_runtime.h>
#include <math.h>

// ---------------- problem constants (NT=1, REAL=512 fixed by harness inputs) --
#define BB    2
#define SS    1024
#define EE    768
#define NH    8
#define DHD   96
#define NL    8
#define FFD   2048
#define VD    32000
#define REALC 512
#define MTOK  (BB*SS)     // 2048 rows for layer ops
#define MACTN (BB*REALC)  // 1024 rows for head ops
#define QKVW  (3*EE)      // 2304
#define WCHUNK 6400       // Wp2 N-chunk (32000 = 5*6400)

// attention tiling
#define QB 64
#define KB 64
#define KS_LD 104   // K LDS row stride (elems), pad 96->104: b128 reads 2-way max
#define VT_LD 72    // V^T LDS row stride (64->72)
#define P_LD  72    // P LDS row stride

typedef __attribute__((ext_vector_type(8))) short bf16x8;
typedef __attribute__((ext_vector_type(4))) float f32x4;

static __device__ __forceinline__ float gelu_exact(float x) {
    return 0.5f * x * (1.0f + erff(x * 0.7071067811865476f));
}
static __device__ __forceinline__ unsigned short f2bf(float f) {
    unsigned int u = __builtin_bit_cast(unsigned int, f);
    unsigned int r = u + 0x7FFFu + ((u >> 16) & 1u);  // RNE (finite values only)
    return (unsigned short)(r >> 16);
}
static __device__ __forceinline__ float bf2f(unsigned short u) {
    union { unsigned int i; float f; } v; v.i = ((unsigned int)u) << 16; return v.f;
}

#define GLDS16(gp, lp) __builtin_amdgcn_global_load_lds( \
    (const __attribute__((address_space(1))) void*)(gp), \
    (__attribute__((address_space(3))) void*)(lp), 16, 0, 0)

// ---------------- fp32 -> bf16 convert (vectorized) -----------------------------
__global__ __launch_bounds__(256) void f2b_kernel(const float* __restrict__ src,
                                                  unsigned short* __restrict__ dst, int n4) {
    int i = blockIdx.x * 256 + threadIdx.x;
    if (i >= n4) return;
    float4 v = ((const float4*)src)[i];
    ushort4 o;
    o.x = f2bf(v.x); o.y = f2bf(v.y); o.z = f2bf(v.z); o.w = f2bf(v.w);
    ((ushort4*)dst)[i] = o;
}

// ---------------- embed: h = x + pe(r) + tpe(p), dual fp32+bf16 out -------------
__global__ __launch_bounds__(256) void embed_kernel(const float* __restrict__ x,
                                                    const float* __restrict__ tpe,
                                                    float* __restrict__ h,
                                                    unsigned short* __restrict__ hb) {
    int idx = blockIdx.x * 256 + threadIdx.x;   // over MTOK*EE
    if (idx >= MTOK * EE) return;
    int e = idx % EE;
    int tok = idx / EE;          // b*SS + s
    int s = tok & (SS - 1);
    int r = s >> 1;              // s / bs
    int p = s & 1;               // s % bs
    int k2 = (e >> 1) * 2;
    double div = exp((double)k2 * (-9.210340371976184 / (double)EE)); // ln(10000)
    double ang = (double)r * div;
    float pe = (e & 1) ? (float)cos(ang) : (float)sin(ang);
    float v = x[idx] + pe + tpe[p * EE + e];
    h[idx] = v;
    hb[idx] = f2bf(v);
}

// ---------------- bf16 MFMA GEMM ------------------------------------------------
// m97 structure: 128x128 tile, BK=64, 4 waves, global_load_lds width-16 staging.
// MODE 0: fp32 out (Cf).  MODE 1: qkv special — q/k cols -> Cb row-major bf16,
//         v cols (c>=1536) -> CvT transposed [c-1536][row] bf16.
// MODE 3: bf16 out + GELU (Cb).
template<int MODE>
__global__ __launch_bounds__(256) void gemm_bf16_kernel(
    const unsigned short* __restrict__ A, const unsigned short* __restrict__ W,
    const float* __restrict__ bias, float* __restrict__ Cf,
    unsigned short* __restrict__ Cb, unsigned short* __restrict__ CvT,
    int M, int N, int K, int ldc) {
    __shared__ unsigned short As[128 * 64];
    __shared__ unsigned short Ws[128 * 64];
    const int bm = blockIdx.y * 128;
    const int bn = blockIdx.x * 128;
    const int t = threadIdx.x;
    const int wave = t >> 6;
    const int lane = t & 63;
    const int wm = (wave >> 1) * 64;
    const int wn = (wave & 1) * 64;
    f32x4 acc[4][4] = {};

    const int srow = wave * 32 + (lane >> 3);
    const int scol = (lane & 7) * 8;
    const unsigned short* gA = A + (size_t)(bm + srow) * K + scol;
    const unsigned short* gW = W + (size_t)(bn + srow) * K + scol;

    for (int k0 = 0; k0 < K; k0 += 64) {
        __syncthreads();
#pragma unroll
        for (int i = 0; i < 4; ++i) {
            GLDS16(gA + (size_t)(i * 8) * K + k0, &As[(wave * 32 + i * 8) * 64]);
            GLDS16(gW + (size_t)(i * 8) * K + k0, &Ws[(wave * 32 + i * 8) * 64]);
        }
        __syncthreads();
#pragma unroll
        for (int ks = 0; ks < 2; ++ks) {
            bf16x8 a[4], b[4];
#pragma unroll
            for (int mi = 0; mi < 4; ++mi)
                a[mi] = *(const bf16x8*)&As[(wm + mi * 16 + (lane & 15)) * 64 + ks * 32 + (lane >> 4) * 8];
#pragma unroll
            for (int ni = 0; ni < 4; ++ni)
                b[ni] = *(const bf16x8*)&Ws[(wn + ni * 16 + (lane & 15)) * 64 + ks * 32 + (lane >> 4) * 8];
#pragma unroll
            for (int mi = 0; mi < 4; ++mi)
#pragma unroll
                for (int ni = 0; ni < 4; ++ni)
                    acc[mi][ni] = __builtin_amdgcn_mfma_f32_16x16x32_bf16(
                        a[mi], b[ni], acc[mi][ni], 0, 0, 0);
        }
    }

    // epilogue: C/D layout col = lane&15, row = (lane>>4)*4 + r
    const bool vpart = (MODE == 1) && (bn >= 2 * EE);   // uniform per block
#pragma unroll
    for (int mi = 0; mi < 4; ++mi) {
#pragma unroll
        for (int ni = 0; ni < 4; ++ni) {
            const int c = bn + wn + ni * 16 + (lane & 15);
            const float bv = bias[c];
            const int rwb = bm + wm + mi * 16 + (lane >> 4) * 4;
            if (vpart) {
                ushort4 pk;
                pk.x = f2bf(acc[mi][ni][0] + bv);
                pk.y = f2bf(acc[mi][ni][1] + bv);
                pk.z = f2bf(acc[mi][ni][2] + bv);
                pk.w = f2bf(acc[mi][ni][3] + bv);
                *(ushort4*)&CvT[(size_t)(c - 2 * EE) * MTOK + rwb] = pk;
            } else {
#pragma unroll
                for (int r = 0; r < 4; ++r) {
                    float v = acc[mi][ni][r] + bv;
                    if (MODE == 3) {
                        v = gelu_exact(v);
                        Cb[(size_t)(rwb + r) * ldc + c] = f2bf(v);
                    } else if (MODE == 1) {
                        Cb[(size_t)(rwb + r) * ldc + c] = f2bf(v);
                    } else {
                        Cf[(size_t)(rwb + r) * ldc + c] = v;
                    }
                }
            }
        }
    }
}

// ---------------- MFMA flash attention ------------------------------------------
// grid (SS/QB=16, BB*NH=16), 256 threads = 4 waves, wave w owns q-rows
// bq + w*16 .. +15. Per K-tile: stage K [64][104] + V^T [96][72] in LDS,
// QK^T mfma, in-register online softmax (shfl butterfly row stats),
// P -> LDS bf16 (wave-local rows), PV mfma. o out fp32.
__global__ __launch_bounds__(256) void attn_mfma_kernel(
    const unsigned short* __restrict__ qkvb,   // [2048][2304] bf16 (v region unused)
    const unsigned short* __restrict__ vT,     // [768][2048] bf16
    float* __restrict__ o) {                   // [2048][768]
    __shared__ unsigned short Ks[KB * KS_LD];
    __shared__ unsigned short VTs[DHD * VT_LD];
    __shared__ unsigned short Ps[QB * P_LD];

    const int bq = blockIdx.x * QB;
    const int hh = blockIdx.y & 7;
    const int b  = blockIdx.y >> 3;
    const int t = threadIdx.x;
    const int w = t >> 6;
    const int lane = t & 63;
    const int lr = lane >> 4;       // 0..3
    const int lc = lane & 15;       // 0..15
    const float scale = 0.10206207261596577f; // 1/sqrt(96)

    // Q a-frags in registers: rows bq + w*16 + lc, d-slice ks*32 + lr*8
    bf16x8 qa[3];
    {
        const unsigned short* qrow = qkvb + (size_t)(b * SS + bq + w * 16 + lc) * QKVW + hh * DHD;
#pragma unroll
        for (int ks = 0; ks < 3; ++ks)
            qa[ks] = *(const bf16x8*)(qrow + ks * 32 + lr * 8);
    }

    f32x4 acc_o[6] = {};
    float m_st[4], l_st[4];
#pragma unroll
    for (int r = 0; r < 4; ++r) { m_st[r] = -1e30f; l_st[r] = 0.f; }
    const int q_row = lr << 2;

    for (int kt = 0; kt < SS / KB; ++kt) {
        __syncthreads();   // all waves' PV reads of prev tile done
        // stage K tile + V^T tile (cooperative, b128 LDS writes)
#pragma unroll
        for (int it = 0; it < 3; ++it) {
            int flat = it * 256 + t;            // 0..767
            int kr = flat / 12;                 // 0..63
            int d8 = (flat % 12) * 8;           // 0..88
            *(bf16x8*)&Ks[kr * KS_LD + d8] =
                *(const bf16x8*)&qkvb[(size_t)(b * SS + kt * KB + kr) * QKVW + EE + hh * DHD + d8];
            int d  = flat >> 3;                 // 0..95
            int k8 = (flat & 7) * 8;            // 0..56
            *(bf16x8*)&VTs[d * VT_LD + k8] =
                *(const bf16x8*)&vT[(size_t)(hh * DHD + d) * MTOK + b * SS + kt * KB + k8];
        }
        __syncthreads();

        // QK^T
        f32x4 sfr[4] = {};
#pragma unroll
        for (int nf = 0; nf < 4; ++nf) {
#pragma unroll
            for (int ks = 0; ks < 3; ++ks) {
                bf16x8 kb = *(const bf16x8*)&Ks[(nf * 16 + lc) * KS_LD + ks * 32 + lr * 8];
                sfr[nf] = __builtin_amdgcn_mfma_f32_16x16x32_bf16(qa[ks], kb, sfr[nf], 0, 0, 0);
            }
        }
        // scale + mask bias (+1.0 where disallowed, per reference)
        const int kbase = kt * KB;
#pragma unroll
        for (int nf = 0; nf < 4; ++nf) {
            const int k = kbase + nf * 16 + lc;
#pragma unroll
            for (int r = 0; r < 4; ++r) {
                const int q = bq + w * 16 + q_row + r;
                bool allowed = (((k >> 1) == (q >> 1)) && ((q & 1) >= (k & 1))) ||
                               (((k & 1) == 0) && (q > k));
                sfr[nf][r] = sfr[nf][r] * scale + (allowed ? 0.f : 1.f);
            }
        }
        // row max (butterfly over the 16 col-lanes)
        float corr[4];
#pragma unroll
        for (int r = 0; r < 4; ++r) {
            float v = fmaxf(fmaxf(sfr[0][r], sfr[1][r]), fmaxf(sfr[2][r], sfr[3][r]));
            v = fmaxf(v, __shfl_xor(v, 1)); v = fmaxf(v, __shfl_xor(v, 2));
            v = fmaxf(v, __shfl_xor(v, 4)); v = fmaxf(v, __shfl_xor(v, 8));
            float mn = fmaxf(m_st[r], v);
            corr[r] = __expf(m_st[r] - mn);
            m_st[r] = mn;
        }
        // P = exp(S - m), row sum, write P (bf16) to wave-local LDS rows
        float rsum[4] = {0.f, 0.f, 0.f, 0.f};
#pragma unroll
        for (int nf = 0; nf < 4; ++nf) {
#pragma unroll
            for (int r = 0; r < 4; ++r) {
                float p = __expf(sfr[nf][r] - m_st[r]);
                rsum[r] += p;
                Ps[(w * 16 + q_row + r) * P_LD + nf * 16 + lc] = f2bf(p);
            }
        }
#pragma unroll
        for (int r = 0; r < 4; ++r) {
            float v = rsum[r];
            v += __shfl_xor(v, 1); v += __shfl_xor(v, 2);
            v += __shfl_xor(v, 4); v += __shfl_xor(v, 8);
            l_st[r] = l_st[r] * corr[r] + v;
        }
#pragma unroll
        for (int nf = 0; nf < 6; ++nf)
#pragma unroll
            for (int r = 0; r < 4; ++r)
                acc_o[nf][r] *= corr[r];
        // PV (Ps rows are wave-local: in-order LDS pipe, no barrier needed)
#pragma unroll
        for (int ks2 = 0; ks2 < 2; ++ks2) {
            bf16x8 pa = *(const bf16x8*)&Ps[(w * 16 + lc) * P_LD + ks2 * 32 + lr * 8];
#pragma unroll
            for (int nf = 0; nf < 6; ++nf) {
                bf16x8 vb = *(const bf16x8*)&VTs[(nf * 16 + lc) * VT_LD + ks2 * 32 + lr * 8];
                acc_o[nf] = __builtin_amdgcn_mfma_f32_16x16x32_bf16(pa, vb, acc_o[nf], 0, 0, 0);
            }
        }
    }
    // epilogue: O = acc / l
#pragma unroll
    for (int nf = 0; nf < 6; ++nf) {
#pragma unroll
        for (int r = 0; r < 4; ++r) {
            const int q = bq + w * 16 + q_row + r;
            o[(size_t)(b * SS + q) * EE + hh * DHD + nf * 16 + lc] = acc_o[nf][r] / l_st[r];
        }
    }
}

// ---------------- layernorm (+residual, +NaN->0), dual out, optional gather ----
template<bool GATHER>
__global__ __launch_bounds__(256) void ln_kernel(const float* __restrict__ a,
                                                 const float* __restrict__ res,
                                                 const float* __restrict__ g,
                                                 const float* __restrict__ beta,
                                                 float* __restrict__ outf,
                                                 unsigned short* __restrict__ outb) {
    __shared__ float rs[256], rs2[256];
    const int row = blockIdx.x;
    const int t = threadIdx.x;
    int src = row;
    if (GATHER) src = (row >> 9) * SS + ((row & 511) << 1) + 1; // act_idx = 2r+1
    const float* pa = a + (size_t)src * EE;
    const float* pr = res ? res + (size_t)src * EE : nullptr;
    float x[3];
    float s = 0.f, s2 = 0.f;
#pragma unroll
    for (int i = 0; i < 3; ++i) {
        int e = t + i * 256;
        float v = pa[e] + (pr ? pr[e] : 0.f);
        x[i] = v; s += v; s2 += v * v;
    }
    rs[t] = s; rs2[t] = s2; __syncthreads();
    for (int k = 128; k > 0; k >>= 1) {
        if (t < k) { rs[t] += rs[t + k]; rs2[t] += rs2[t + k]; }
        __syncthreads();
    }
    const float mean = rs[0] * (1.0f / EE);
    const float var  = rs2[0] * (1.0f / EE) - mean * mean;
    const float rstd = 1.0f / sqrtf(var + 1e-5f);
#pragma unroll
    for (int i = 0; i < 3; ++i) {
        int e = t + i * 256;
        float v = (x[i] - mean) * rstd * g[e] + beta[e];
        if (isnan(v)) v = 0.f;  // nan_to_num
        if (outf) outf[(size_t)row * EE + e] = v;
        if (outb) outb[(size_t)row * EE + e] = f2bf(v);
    }
}

// ---------------- value head second GEMM (N=1), bf16 input ---------------------
__global__ __launch_bounds__(256) void value2_kernel(const unsigned short* __restrict__ v1,
                                                     const float* __restrict__ Wv2,
                                                     const float* __restrict__ bv2,
                                                     float* __restrict__ out) {
    __shared__ float red[256];
    const int row = blockIdx.x;
    const int t = threadIdx.x;
    const unsigned short* pr = v1 + (size_t)row * FFD;
    float s = 0.f;
    for (int i = t; i < FFD; i += 256) s = fmaf(bf2f(pr[i]), Wv2[i], s);
    red[t] = s; __syncthreads();
    for (int k = 128; k > 0; k >>= 1) {
        if (t < k) red[t] += red[t + k];
        __syncthreads();
    }
    if (t == 0) out[row] = red[0] + bv2[0];
}

// ---------------- launch --------------------------------------------------------
extern "C" void kernel_launch(void* const* d_in, const int* in_sizes, int n_in,
                              void* d_out, int out_size, void* d_ws, size_t ws_size,
                              hipStream_t stream) {
    const float* x    = (const float*)d_in[0];
    const float* tpe  = (const float*)d_in[1];
    const float* Wqkv = (const float*)d_in[2];
    const float* bqkv = (const float*)d_in[3];
    const float* W1   = (const float*)d_in[4];
    const float* b1   = (const float*)d_in[5];
    const float* W2   = (const float*)d_in[6];
    const float* b2   = (const float*)d_in[7];
    const float* g1   = (const float*)d_in[8];
    const float* be1  = (const float*)d_in[9];
    const float* g2   = (const float*)d_in[10];
    const float* be2  = (const float*)d_in[11];
    const float* gf   = (const float*)d_in[12];
    const float* bf   = (const float*)d_in[13];
    const float* Wp1  = (const float*)d_in[14];
    const float* bp1  = (const float*)d_in[15];
    const float* Wp2  = (const float*)d_in[16];
    const float* bp2  = (const float*)d_in[17];
    const float* Wv1  = (const float*)d_in[18];
    const float* bv1  = (const float*)d_in[19];
    const float* Wv2  = (const float*)d_in[20];
    const float* bv2  = (const float*)d_in[21];

    // ---- workspace layout ----
    float* ws  = (float*)d_ws;
    float* h   = ws;                        // 2048*768
    float* o   = h  + (size_t)MTOK * EE;    // 2048*768
    float* hc  = o  + (size_t)MTOK * EE;    // 2048*768
    float* ff2 = hc + (size_t)MTOK * EE;    // 2048*768
    unsigned short* bws = (unsigned short*)(ff2 + (size_t)MTOK * EE);
    unsigned short* h_bf   = bws;                                   // 2048*768
    unsigned short* hc_bf  = h_bf   + (size_t)MTOK * EE;            // 2048*768
    unsigned short* ff1_bf = hc_bf  + (size_t)MTOK * EE;            // 2048*2048
    unsigned short* act_bf = ff1_bf + (size_t)MTOK * FFD;           // 1024*768
    unsigned short* p1_bf  = act_bf + (size_t)MACTN * EE;           // 1024*2048
    unsigned short* qkv_bf = p1_bf  + (size_t)MACTN * FFD;          // 2048*2304
    unsigned short* vT     = qkv_bf + (size_t)MTOK * QKVW;          // 768*2048
    unsigned short* wq_bf  = vT     + (size_t)EE * MTOK;            // 2304*768
    unsigned short* w1_bf  = wq_bf  + (size_t)QKVW * EE;            // 2048*768
    unsigned short* w2_bf  = w1_bf  + (size_t)FFD * EE;             // 768*2048
    unsigned short* wp2c   = w2_bf  + (size_t)EE * FFD;             // 6400*2048
    unsigned short* wp1_bf = wq_bf;  // reuse
    unsigned short* wv1_bf = w1_bf;  // reuse
    // total ~= 94 MB

    float* pol = (float*)d_out;                       // 1024*32000
    float* val = (float*)d_out + (size_t)MACTN * VD;  // 1024

    const int C256 = 256;
#define NBLK(n) (((n) + 255) / 256)
#define CONV(src, dst, n) f2b_kernel<<<NBLK((n) / 4), C256, 0, stream>>>(src, dst, (n) / 4)

    embed_kernel<<<NBLK(MTOK * EE), C256, 0, stream>>>(x, tpe, h, h_bf);

    for (int l = 0; l < NL; ++l) {
        CONV(Wqkv + (size_t)l * QKVW * EE, wq_bf, QKVW * EE);
        CONV(W1   + (size_t)l * FFD * EE,  w1_bf, FFD * EE);
        CONV(W2   + (size_t)l * EE * FFD,  w2_bf, EE * FFD);

        gemm_bf16_kernel<1><<<dim3(QKVW / 128, MTOK / 128), C256, 0, stream>>>(
            h_bf, wq_bf, bqkv + (size_t)l * QKVW, nullptr, qkv_bf, vT, MTOK, QKVW, EE, QKVW);
        attn_mfma_kernel<<<dim3(SS / QB, BB * NH), C256, 0, stream>>>(qkv_bf, vT, o);
        ln_kernel<false><<<MTOK, C256, 0, stream>>>(h, o, g1 + l * EE, be1 + l * EE, hc, hc_bf);
        gemm_bf16_kernel<3><<<dim3(FFD / 128, MTOK / 128), C256, 0, stream>>>(
            hc_bf, w1_bf, b1 + (size_t)l * FFD, nullptr, ff1_bf, nullptr, MTOK, FFD, EE, FFD);
        gemm_bf16_kernel<0><<<dim3(EE / 128, MTOK / 128), C256, 0, stream>>>(
            ff1_bf, w2_bf, b2 + (size_t)l * EE, ff2, nullptr, nullptr, MTOK, EE, FFD, EE);
        ln_kernel<false><<<MTOK, C256, 0, stream>>>(hc, ff2, g2 + l * EE, be2 + l * EE, h, h_bf);
    }

    // final LN on the 1024 action rows (act_idx = 2r+1), bf16 out only
    ln_kernel<true><<<MACTN, C256, 0, stream>>>(h, nullptr, gf, bf, nullptr, act_bf);

    // policy head
    CONV(Wp1, wp1_bf, FFD * EE);
    gemm_bf16_kernel<3><<<dim3(FFD / 128, MACTN / 128), C256, 0, stream>>>(
        act_bf, wp1_bf, bp1, nullptr, p1_bf, nullptr, MACTN, FFD, EE, FFD);
    for (int c = 0; c < VD / WCHUNK; ++c) {
        CONV(Wp2 + (size_t)c * WCHUNK * FFD, wp2c, WCHUNK * FFD);
        gemm_bf16_kernel<0><<<dim3(WCHUNK / 128, MACTN / 128), C256, 0, stream>>>(
            p1_bf, wp2c, bp2 + (size_t)c * WCHUNK, pol + (size_t)c * WCHUNK, nullptr, nullptr,
            MACTN, WCHUNK, FFD, VD);
    }

    // value head (reuse p1_bf after policy GEMM consumed it)
    CONV(Wv1, wv1_bf, FFD * EE);
    gemm_bf16_kernel<3><<<dim3(FFD / 128, MACTN / 128), C256, 0, stream>>>(
        act_bf, wv1_bf, bv1, nullptr, p1_bf, nullptr, MACTN, FFD, EE, FFD);
    value2_kernel<<<MACTN, C256, 0, stream>>>(p1_bf, Wv2, bv2, val);
#undef CONV
#undef NBLK
}

// Round 4
// 1589.138 us; speedup vs baseline: 8.2554x; 1.0163x over previous
//
#include <hip/hip_runtime.h>
#include <math.h>

// ---------------- problem constants (NT=1, REAL=512 fixed by harness inputs) --
#define BB    2
#define SS    1024
#define EE    768
#define NH    8
#define DHD   96
#define NL    8
#define FFD   2048
#define VD    32000
#define REALC 512
#define MTOK  (BB*SS)     // 2048 rows for layer ops
#define MACTN (BB*REALC)  // 1024 rows for head ops
#define QKVW  (3*EE)      // 2304

// attention tiling
#define QB 64
#define KB 64
#define KS_LD 104   // K LDS row stride (elems)
#define VT_LD 72    // V^T LDS row stride
#define P_LD  72    // P LDS row stride

typedef __attribute__((ext_vector_type(8))) short bf16x8;
typedef __attribute__((ext_vector_type(4))) float f32x4;

static __device__ __forceinline__ float gelu_exact(float x) {
    return 0.5f * x * (1.0f + erff(x * 0.7071067811865476f));
}
static __device__ __forceinline__ unsigned short f2bf(float f) {
    unsigned int u = __builtin_bit_cast(unsigned int, f);
    unsigned int r = u + 0x7FFFu + ((u >> 16) & 1u);  // RNE (finite values only)
    return (unsigned short)(r >> 16);
}
static __device__ __forceinline__ float bf2f(unsigned short u) {
    union { unsigned int i; float f; } v; v.i = ((unsigned int)u) << 16; return v.f;
}

#define GLDS16(gp, lp) __builtin_amdgcn_global_load_lds( \
    (const __attribute__((address_space(1))) void*)(gp), \
    (__attribute__((address_space(3))) void*)(lp), 16, 0, 0)

// ---------------- fp32 -> bf16 convert (vectorized) -----------------------------
__global__ __launch_bounds__(256) void f2b_kernel(const float* __restrict__ src,
                                                  unsigned short* __restrict__ dst, int n4) {
    int i = blockIdx.x * 256 + threadIdx.x;
    if (i >= n4) return;
    float4 v = ((const float4*)src)[i];
    ushort4 o;
    o.x = f2bf(v.x); o.y = f2bf(v.y); o.z = f2bf(v.z); o.w = f2bf(v.w);
    ((ushort4*)dst)[i] = o;
}

// ---------------- embed: h = x + pe(r) + tpe(p), dual fp32+bf16 out -------------
__global__ __launch_bounds__(256) void embed_kernel(const float* __restrict__ x,
                                                    const float* __restrict__ tpe,
                                                    float* __restrict__ h,
                                                    unsigned short* __restrict__ hb) {
    int idx = blockIdx.x * 256 + threadIdx.x;   // over MTOK*EE
    if (idx >= MTOK * EE) return;
    int e = idx % EE;
    int tok = idx / EE;          // b*SS + s
    int s = tok & (SS - 1);
    int r = s >> 1;              // s / bs
    int p = s & 1;               // s % bs
    int k2 = (e >> 1) * 2;
    double div = exp((double)k2 * (-9.210340371976184 / (double)EE)); // ln(10000)
    double ang = (double)r * div;
    float pe = (e & 1) ? (float)cos(ang) : (float)sin(ang);
    float v = x[idx] + pe + tpe[p * EE + e];
    h[idx] = v;
    hb[idx] = f2bf(v);
}

// ---------------- bf16 MFMA GEMM (128x128 tile, m97 structure) ------------------
// MODE 0: fp32 out (Cf).  MODE 1: qkv special — q/k cols -> Cb row-major bf16,
//         v cols (c>=1536) -> CvT transposed [c-1536][row] bf16.
// MODE 3: bf16 out + GELU (Cb).
template<int MODE>
__global__ __launch_bounds__(256) void gemm_bf16_kernel(
    const unsigned short* __restrict__ A, const unsigned short* __restrict__ W,
    const float* __restrict__ bias, float* __restrict__ Cf,
    unsigned short* __restrict__ Cb, unsigned short* __restrict__ CvT,
    int M, int N, int K, int ldc) {
    __shared__ unsigned short As[128 * 64];
    __shared__ unsigned short Ws[128 * 64];
    const int bm = blockIdx.y * 128;
    const int bn = blockIdx.x * 128;
    const int t = threadIdx.x;
    const int wave = t >> 6;
    const int lane = t & 63;
    const int wm = (wave >> 1) * 64;
    const int wn = (wave & 1) * 64;
    f32x4 acc[4][4] = {};

    const int srow = wave * 32 + (lane >> 3);
    const int scol = (lane & 7) * 8;
    const unsigned short* gA = A + (size_t)(bm + srow) * K + scol;
    const unsigned short* gW = W + (size_t)(bn + srow) * K + scol;

    for (int k0 = 0; k0 < K; k0 += 64) {
        __syncthreads();
#pragma unroll
        for (int i = 0; i < 4; ++i) {
            GLDS16(gA + (size_t)(i * 8) * K + k0, &As[(wave * 32 + i * 8) * 64]);
            GLDS16(gW + (size_t)(i * 8) * K + k0, &Ws[(wave * 32 + i * 8) * 64]);
        }
        __syncthreads();
#pragma unroll
        for (int ks = 0; ks < 2; ++ks) {
            bf16x8 a[4], b[4];
#pragma unroll
            for (int mi = 0; mi < 4; ++mi)
                a[mi] = *(const bf16x8*)&As[(wm + mi * 16 + (lane & 15)) * 64 + ks * 32 + (lane >> 4) * 8];
#pragma unroll
            for (int ni = 0; ni < 4; ++ni)
                b[ni] = *(const bf16x8*)&Ws[(wn + ni * 16 + (lane & 15)) * 64 + ks * 32 + (lane >> 4) * 8];
#pragma unroll
            for (int mi = 0; mi < 4; ++mi)
#pragma unroll
                for (int ni = 0; ni < 4; ++ni)
                    acc[mi][ni] = __builtin_amdgcn_mfma_f32_16x16x32_bf16(
                        a[mi], b[ni], acc[mi][ni], 0, 0, 0);
        }
    }

    const bool vpart = (MODE == 1) && (bn >= 2 * EE);   // uniform per block
#pragma unroll
    for (int mi = 0; mi < 4; ++mi) {
#pragma unroll
        for (int ni = 0; ni < 4; ++ni) {
            const int c = bn + wn + ni * 16 + (lane & 15);
            const float bv = bias[c];
            const int rwb = bm + wm + mi * 16 + (lane >> 4) * 4;
            if (vpart) {
                ushort4 pk;
                pk.x = f2bf(acc[mi][ni][0] + bv);
                pk.y = f2bf(acc[mi][ni][1] + bv);
                pk.z = f2bf(acc[mi][ni][2] + bv);
                pk.w = f2bf(acc[mi][ni][3] + bv);
                *(ushort4*)&CvT[(size_t)(c - 2 * EE) * MTOK + rwb] = pk;
            } else {
#pragma unroll
                for (int r = 0; r < 4; ++r) {
                    float v = acc[mi][ni][r] + bv;
                    if (MODE == 3) {
                        v = gelu_exact(v);
                        Cb[(size_t)(rwb + r) * ldc + c] = f2bf(v);
                    } else if (MODE == 1) {
                        Cb[(size_t)(rwb + r) * ldc + c] = f2bf(v);
                    } else {
                        Cf[(size_t)(rwb + r) * ldc + c] = v;
                    }
                }
            }
        }
    }
}

// ---------------- policy GEMM: 128x256 tile, K=2048, XCD-aware grid -------------
// pol[1024][32000] = p1[1024][2048] @ Wp2^T + bp2.  Grid: 1024 linear blocks,
// decode keeps one N-tile's 8 M-blocks on one XCD (B-panel L2 reuse).
// 4 waves (2Mx2N), wave tile 64x128: 64 MFMA : 24 ds_read_b128 per K-step.
__global__ __launch_bounds__(256, 2) void gemm_policy_kernel(
    const unsigned short* __restrict__ A, const unsigned short* __restrict__ W,
    const float* __restrict__ bias, float* __restrict__ C) {
    const int id = blockIdx.x;
    const int xcd = id & 7;
    const int rest = id >> 3;
    const int mt = rest & 7;            // 0..7   M-tile
    const int nt = (rest >> 3) * 8 + xcd; // 0..127 N-tile
    if (nt >= VD / 256) return;         // uniform early-exit (24 idle blocks)
    const int bm = mt * 128;
    const int bn = nt * 256;
    const int K = FFD;

    __shared__ unsigned short As[128 * 64];
    __shared__ unsigned short Bs[256 * 64];
    const int t = threadIdx.x;
    const int w = t >> 6;
    const int lane = t & 63;
    const int wm = (w >> 1) * 64;
    const int wn = (w & 1) * 128;
    f32x4 acc[4][8] = {};

    const int rr8 = (w << 3) + (lane >> 3);   // staging row within 32-row group
    const int cc8 = (lane & 7) * 8;
    const unsigned short* gA = A + (size_t)(bm + rr8) * K + cc8;
    const unsigned short* gB = W + (size_t)(bn + rr8) * K + cc8;

    for (int k0 = 0; k0 < K; k0 += 64) {
        __syncthreads();
#pragma unroll
        for (int i = 0; i < 4; ++i)
            GLDS16(gA + (size_t)(i * 32) * K + k0, &As[((w << 3) + i * 32) * 64]);
#pragma unroll
        for (int i = 0; i < 8; ++i)
            GLDS16(gB + (size_t)(i * 32) * K + k0, &Bs[((w << 3) + i * 32) * 64]);
        __syncthreads();
#pragma unroll
        for (int ks = 0; ks < 2; ++ks) {
            bf16x8 a[4], b[8];
#pragma unroll
            for (int mi = 0; mi < 4; ++mi)
                a[mi] = *(const bf16x8*)&As[(wm + mi * 16 + (lane & 15)) * 64 + ks * 32 + (lane >> 4) * 8];
#pragma unroll
            for (int ni = 0; ni < 8; ++ni)
                b[ni] = *(const bf16x8*)&Bs[(wn + ni * 16 + (lane & 15)) * 64 + ks * 32 + (lane >> 4) * 8];
#pragma unroll
            for (int mi = 0; mi < 4; ++mi)
#pragma unroll
                for (int ni = 0; ni < 8; ++ni)
                    acc[mi][ni] = __builtin_amdgcn_mfma_f32_16x16x32_bf16(
                        a[mi], b[ni], acc[mi][ni], 0, 0, 0);
        }
    }
#pragma unroll
    for (int mi = 0; mi < 4; ++mi) {
#pragma unroll
        for (int ni = 0; ni < 8; ++ni) {
            const int c = bn + wn + ni * 16 + (lane & 15);
            const float bv = bias[c];
            const int rwb = bm + wm + mi * 16 + (lane >> 4) * 4;
#pragma unroll
            for (int r = 0; r < 4; ++r)
                C[(size_t)(rwb + r) * VD + c] = acc[mi][ni][r] + bv;
        }
    }
}

// ---------------- MFMA flash attention ------------------------------------------
__global__ __launch_bounds__(256) void attn_mfma_kernel(
    const unsigned short* __restrict__ qkvb,   // [2048][2304] bf16 (v region unused)
    const unsigned short* __restrict__ vT,     // [768][2048] bf16
    float* __restrict__ o) {                   // [2048][768]
    __shared__ unsigned short Ks[KB * KS_LD];
    __shared__ unsigned short VTs[DHD * VT_LD];
    __shared__ unsigned short Ps[QB * P_LD];

    const int bq = blockIdx.x * QB;
    const int hh = blockIdx.y & 7;
    const int b  = blockIdx.y >> 3;
    const int t = threadIdx.x;
    const int w = t >> 6;
    const int lane = t & 63;
    const int lr = lane >> 4;       // 0..3
    const int lc = lane & 15;       // 0..15
    const float scale = 0.10206207261596577f; // 1/sqrt(96)

    bf16x8 qa[3];
    {
        const unsigned short* qrow = qkvb + (size_t)(b * SS + bq + w * 16 + lc) * QKVW + hh * DHD;
#pragma unroll
        for (int ks = 0; ks < 3; ++ks)
            qa[ks] = *(const bf16x8*)(qrow + ks * 32 + lr * 8);
    }

    f32x4 acc_o[6] = {};
    float m_st[4], l_st[4];
#pragma unroll
    for (int r = 0; r < 4; ++r) { m_st[r] = -1e30f; l_st[r] = 0.f; }
    const int q_row = lr << 2;

    for (int kt = 0; kt < SS / KB; ++kt) {
        __syncthreads();
#pragma unroll
        for (int it = 0; it < 3; ++it) {
            int flat = it * 256 + t;            // 0..767
            int kr = flat / 12;                 // 0..63
            int d8 = (flat % 12) * 8;           // 0..88
            *(bf16x8*)&Ks[kr * KS_LD + d8] =
                *(const bf16x8*)&qkvb[(size_t)(b * SS + kt * KB + kr) * QKVW + EE + hh * DHD + d8];
            int d  = flat >> 3;                 // 0..95
            int k8 = (flat & 7) * 8;            // 0..56
            *(bf16x8*)&VTs[d * VT_LD + k8] =
                *(const bf16x8*)&vT[(size_t)(hh * DHD + d) * MTOK + b * SS + kt * KB + k8];
        }
        __syncthreads();

        f32x4 sfr[4] = {};
#pragma unroll
        for (int nf = 0; nf < 4; ++nf) {
#pragma unroll
            for (int ks = 0; ks < 3; ++ks) {
                bf16x8 kb = *(const bf16x8*)&Ks[(nf * 16 + lc) * KS_LD + ks * 32 + lr * 8];
                sfr[nf] = __builtin_amdgcn_mfma_f32_16x16x32_bf16(qa[ks], kb, sfr[nf], 0, 0, 0);
            }
        }
        const int kbase = kt * KB;
#pragma unroll
        for (int nf = 0; nf < 4; ++nf) {
            const int k = kbase + nf * 16 + lc;
#pragma unroll
            for (int r = 0; r < 4; ++r) {
                const int q = bq + w * 16 + q_row + r;
                bool allowed = (((k >> 1) == (q >> 1)) && ((q & 1) >= (k & 1))) ||
                               (((k & 1) == 0) && (q > k));
                sfr[nf][r] = sfr[nf][r] * scale + (allowed ? 0.f : 1.f);
            }
        }
        float corr[4];
#pragma unroll
        for (int r = 0; r < 4; ++r) {
            float v = fmaxf(fmaxf(sfr[0][r], sfr[1][r]), fmaxf(sfr[2][r], sfr[3][r]));
            v = fmaxf(v, __shfl_xor(v, 1)); v = fmaxf(v, __shfl_xor(v, 2));
            v = fmaxf(v, __shfl_xor(v, 4)); v = fmaxf(v, __shfl_xor(v, 8));
            float mn = fmaxf(m_st[r], v);
            corr[r] = __expf(m_st[r] - mn);
            m_st[r] = mn;
        }
        float rsum[4] = {0.f, 0.f, 0.f, 0.f};
#pragma unroll
        for (int nf = 0; nf < 4; ++nf) {
#pragma unroll
            for (int r = 0; r < 4; ++r) {
                float p = __expf(sfr[nf][r] - m_st[r]);
                rsum[r] += p;
                Ps[(w * 16 + q_row + r) * P_LD + nf * 16 + lc] = f2bf(p);
            }
        }
#pragma unroll
        for (int r = 0; r < 4; ++r) {
            float v = rsum[r];
            v += __shfl_xor(v, 1); v += __shfl_xor(v, 2);
            v += __shfl_xor(v, 4); v += __shfl_xor(v, 8);
            l_st[r] = l_st[r] * corr[r] + v;
        }
#pragma unroll
        for (int nf = 0; nf < 6; ++nf)
#pragma unroll
            for (int r = 0; r < 4; ++r)
                acc_o[nf][r] *= corr[r];
#pragma unroll
        for (int ks2 = 0; ks2 < 2; ++ks2) {
            bf16x8 pa = *(const bf16x8*)&Ps[(w * 16 + lc) * P_LD + ks2 * 32 + lr * 8];
#pragma unroll
            for (int nf = 0; nf < 6; ++nf) {
                bf16x8 vb = *(const bf16x8*)&VTs[(nf * 16 + lc) * VT_LD + ks2 * 32 + lr * 8];
                acc_o[nf] = __builtin_amdgcn_mfma_f32_16x16x32_bf16(pa, vb, acc_o[nf], 0, 0, 0);
            }
        }
    }
#pragma unroll
    for (int nf = 0; nf < 6; ++nf) {
#pragma unroll
        for (int r = 0; r < 4; ++r) {
            const int q = bq + w * 16 + q_row + r;
            o[(size_t)(b * SS + q) * EE + hh * DHD + nf * 16 + lc] = acc_o[nf][r] / l_st[r];
        }
    }
}

// ---------------- layernorm (+residual, +NaN->0), dual out, optional gather ----
template<bool GATHER>
__global__ __launch_bounds__(256) void ln_kernel(const float* __restrict__ a,
                                                 const float* __restrict__ res,
                                                 const float* __restrict__ g,
                                                 const float* __restrict__ beta,
                                                 float* __restrict__ outf,
                                                 unsigned short* __restrict__ outb) {
    __shared__ float rs[256], rs2[256];
    const int row = blockIdx.x;
    const int t = threadIdx.x;
    int src = row;
    if (GATHER) src = (row >> 9) * SS + ((row & 511) << 1) + 1; // act_idx = 2r+1
    const float* pa = a + (size_t)src * EE;
    const float* pr = res ? res + (size_t)src * EE : nullptr;
    float x[3];
    float s = 0.f, s2 = 0.f;
#pragma unroll
    for (int i = 0; i < 3; ++i) {
        int e = t + i * 256;
        float v = pa[e] + (pr ? pr[e] : 0.f);
        x[i] = v; s += v; s2 += v * v;
    }
    rs[t] = s; rs2[t] = s2; __syncthreads();
    for (int k = 128; k > 0; k >>= 1) {
        if (t < k) { rs[t] += rs[t + k]; rs2[t] += rs2[t + k]; }
        __syncthreads();
    }
    const float mean = rs[0] * (1.0f / EE);
    const float var  = rs2[0] * (1.0f / EE) - mean * mean;
    const float rstd = 1.0f / sqrtf(var + 1e-5f);
#pragma unroll
    for (int i = 0; i < 3; ++i) {
        int e = t + i * 256;
        float v = (x[i] - mean) * rstd * g[e] + beta[e];
        if (isnan(v)) v = 0.f;  // nan_to_num
        if (outf) outf[(size_t)row * EE + e] = v;
        if (outb) outb[(size_t)row * EE + e] = f2bf(v);
    }
}

// ---------------- value head second GEMM (N=1), bf16 input ---------------------
__global__ __launch_bounds__(256) void value2_kernel(const unsigned short* __restrict__ v1,
                                                     const float* __restrict__ Wv2,
                                                     const float* __restrict__ bv2,
                                                     float* __restrict__ out) {
    __shared__ float red[256];
    const int row = blockIdx.x;
    const int t = threadIdx.x;
    const unsigned short* pr = v1 + (size_t)row * FFD;
    float s = 0.f;
    for (int i = t; i < FFD; i += 256) s = fmaf(bf2f(pr[i]), Wv2[i], s);
    red[t] = s; __syncthreads();
    for (int k = 128; k > 0; k >>= 1) {
        if (t < k) red[t] += red[t + k];
        __syncthreads();
    }
    if (t == 0) out[row] = red[0] + bv2[0];
}

// ---------------- launch --------------------------------------------------------
extern "C" void kernel_launch(void* const* d_in, const int* in_sizes, int n_in,
                              void* d_out, int out_size, void* d_ws, size_t ws_size,
                              hipStream_t stream) {
    const float* x    = (const float*)d_in[0];
    const float* tpe  = (const float*)d_in[1];
    const float* Wqkv = (const float*)d_in[2];
    const float* bqkv = (const float*)d_in[3];
    const float* W1   = (const float*)d_in[4];
    const float* b1   = (const float*)d_in[5];
    const float* W2   = (const float*)d_in[6];
    const float* b2   = (const float*)d_in[7];
    const float* g1   = (const float*)d_in[8];
    const float* be1  = (const float*)d_in[9];
    const float* g2   = (const float*)d_in[10];
    const float* be2  = (const float*)d_in[11];
    const float* gf   = (const float*)d_in[12];
    const float* bf   = (const float*)d_in[13];
    const float* Wp1  = (const float*)d_in[14];
    const float* bp1  = (const float*)d_in[15];
    const float* Wp2  = (const float*)d_in[16];
    const float* bp2  = (const float*)d_in[17];
    const float* Wv1  = (const float*)d_in[18];
    const float* bv1  = (const float*)d_in[19];
    const float* Wv2  = (const float*)d_in[20];
    const float* bv2  = (const float*)d_in[21];

    // ---- workspace layout ----
    float* ws  = (float*)d_ws;
    float* h   = ws;                        // 2048*768
    float* o   = h  + (size_t)MTOK * EE;    // 2048*768
    float* hc  = o  + (size_t)MTOK * EE;    // 2048*768
    float* ff2 = hc + (size_t)MTOK * EE;    // 2048*768
    unsigned short* bws = (unsigned short*)(ff2 + (size_t)MTOK * EE);
    unsigned short* h_bf    = bws;                                   // 2048*768
    unsigned short* hc_bf   = h_bf    + (size_t)MTOK * EE;           // 2048*768
    unsigned short* ff1_bf  = hc_bf   + (size_t)MTOK * EE;           // 2048*2048
    unsigned short* act_bf  = ff1_bf  + (size_t)MTOK * FFD;          // 1024*768
    unsigned short* p1_bf   = act_bf  + (size_t)MACTN * EE;          // 1024*2048
    unsigned short* qkv_bf  = p1_bf   + (size_t)MACTN * FFD;         // 2048*2304
    unsigned short* vT      = qkv_bf  + (size_t)MTOK * QKVW;         // 768*2048
    unsigned short* wq_all  = vT      + (size_t)EE * MTOK;           // 8*2304*768
    unsigned short* w1_all  = wq_all  + (size_t)NL * QKVW * EE;      // 8*2048*768
    unsigned short* w2_all  = w1_all  + (size_t)NL * FFD * EE;       // 8*768*2048
    unsigned short* wp1_bf  = w2_all  + (size_t)NL * EE * FFD;       // 2048*768
    unsigned short* wv1_bf  = wp1_bf  + (size_t)FFD * EE;            // 2048*768
    unsigned short* wp2_bf  = wv1_bf  + (size_t)FFD * EE;            // 32000*2048
    // total ~= 275 MB (ws is ~1 GB per poison-fill size)

    float* pol = (float*)d_out;                       // 1024*32000
    float* val = (float*)d_out + (size_t)MACTN * VD;  // 1024

    const int C256 = 256;
#define NBLK(n) (((n) + 255) / 256)
#define CONV(src, dst, n) f2b_kernel<<<NBLK((n) / 4), C256, 0, stream>>>(src, dst, (int)((n) / 4))

    embed_kernel<<<NBLK(MTOK * EE), C256, 0, stream>>>(x, tpe, h, h_bf);

    // all weight converts, batched up-front (6 dispatches)
    CONV(Wqkv, wq_all, (size_t)NL * QKVW * EE);
    CONV(W1,   w1_all, (size_t)NL * FFD * EE);
    CONV(W2,   w2_all, (size_t)NL * EE * FFD);
    CONV(Wp1,  wp1_bf, (size_t)FFD * EE);
    CONV(Wv1,  wv1_bf, (size_t)FFD * EE);
    CONV(Wp2,  wp2_bf, (size_t)VD * FFD);

    for (int l = 0; l < NL; ++l) {
        gemm_bf16_kernel<1><<<dim3(QKVW / 128, MTOK / 128), C256, 0, stream>>>(
            h_bf, wq_all + (size_t)l * QKVW * EE, bqkv + (size_t)l * QKVW,
            nullptr, qkv_bf, vT, MTOK, QKVW, EE, QKVW);
        attn_mfma_kernel<<<dim3(SS / QB, BB * NH), C256, 0, stream>>>(qkv_bf, vT, o);
        ln_kernel<false><<<MTOK, C256, 0, stream>>>(h, o, g1 + l * EE, be1 + l * EE, hc, hc_bf);
        gemm_bf16_kernel<3><<<dim3(FFD / 128, MTOK / 128), C256, 0, stream>>>(
            hc_bf, w1_all + (size_t)l * FFD * EE, b1 + (size_t)l * FFD,
            nullptr, ff1_bf, nullptr, MTOK, FFD, EE, FFD);
        gemm_bf16_kernel<0><<<dim3(EE / 128, MTOK / 128), C256, 0, stream>>>(
            ff1_bf, w2_all + (size_t)l * EE * FFD, b2 + (size_t)l * EE,
            ff2, nullptr, nullptr, MTOK, EE, FFD, EE);
        ln_kernel<false><<<MTOK, C256, 0, stream>>>(hc, ff2, g2 + l * EE, be2 + l * EE, h, h_bf);
    }

    // final LN on the 1024 action rows (act_idx = 2r+1), bf16 out only
    ln_kernel<true><<<MACTN, C256, 0, stream>>>(h, nullptr, gf, bf, nullptr, act_bf);

    // policy head: p1 = gelu(act @ Wp1^T), pol = p1 @ Wp2^T + bp2 (single dispatch)
    gemm_bf16_kernel<3><<<dim3(FFD / 128, MACTN / 128), C256, 0, stream>>>(
        act_bf, wp1_bf, bp1, nullptr, p1_bf, nullptr, MACTN, FFD, EE, FFD);
    gemm_policy_kernel<<<1024, C256, 0, stream>>>(p1_bf, wp2_bf, bp2, pol);

    // value head (reuse p1_bf after policy GEMM consumed it)
    gemm_bf16_kernel<3><<<dim3(FFD / 128, MACTN / 128), C256, 0, stream>>>(
        act_bf, wv1_bf, bv1, nullptr, p1_bf, nullptr, MACTN, FFD, EE, FFD);
    value2_kernel<<<MACTN, C256, 0, stream>>>(p1_bf, Wv2, bv2, val);
#undef CONV
#undef NBLK
}